// Round 26
// baseline (836.402 us; speedup 1.0000x reference)
//
#include <hip/hip_runtime.h>
#include <math.h>

#define HH 200
#define WW 200
#define HWP 40000
#define NP4 10000
#define BB 4

#define LKS 40   // lkconv LDS row stride (u32 entries)
#define DPS 24   // dwgelu LDS row stride
#define PARTSZ 2560000    // one (B,16,H,W) partial buffer (lkconv)

typedef __fp16 f16x2 __attribute__((ext_vector_type(2)));
typedef __fp16 f16x8 __attribute__((ext_vector_type(8)));
typedef float fx4 __attribute__((ext_vector_type(4)));

#if __has_builtin(__builtin_amdgcn_fdot2)
__device__ __forceinline__ float fdot2f(f16x2 a, f16x2 b, float c) {
    return __builtin_amdgcn_fdot2(a, b, c, false);
}
#else
__device__ __forceinline__ float fdot2f(f16x2 a, f16x2 b, float c) {
    return c + (float)a[0] * (float)b[0] + (float)a[1] * (float)b[1];
}
#endif

__device__ __forceinline__ f16x2 pk2(float a, float b) {
    return __builtin_amdgcn_cvt_pkrtz(a, b);
}

__device__ __forceinline__ float gelu_f(float x) {
    return 0.5f * x * (1.0f + erff(x * 0.7071067811865475f));
}

// ---------------- pconv weight pack (ci,co) f16x2 ----------------
__global__ __launch_bounds__(256) void prep_kernel(
    const float* __restrict__ pc, f16x2* __restrict__ wth)
{
    int i = blockIdx.x * 256 + threadIdx.x;
    if (i >= 4096) return;
    int w = i >> 11;
    int r = i & 2047;
    int c2 = r / 64, o = r - c2 * 64;
    const float* src = pc + w * 4096;
    f16x2 v;
    v[0] = (__fp16)src[o * 64 + 2 * c2];
    v[1] = (__fp16)src[o * 64 + 2 * c2 + 1];
    wth[w * 2048 + r] = v;
}

// ------- MFMA A-fragment prep for Ci=64 1x1 convs (ksteps=2) -------
__global__ __launch_bounds__(256) void prepA_kernel(
    const float* __restrict__ qkvw, const float* __restrict__ pp,
    const float* __restrict__ ao, const float* __restrict__ fp,
    f16x8* __restrict__ wA)
{
    int s = blockIdx.x * 256 + threadIdx.x;
    if (s >= 4352) return;
    const float* src;
    int base;
    if (s < 1536)      { src = qkvw;      base = 0; }
    else if (s < 2560) { src = pp;        base = 1536; }
    else if (s < 3072) { src = ao;        base = 2560; }
    else if (s < 3712) { src = fp;        base = 3072; }
    else               { src = fp + 5120; base = 3712; }
    int r = s - base;
    int lane = r & 63;
    int t = r >> 6;
    int ks = t & 1;
    int cot = t >> 1;
    int co = cot * 16 + (lane & 15);
    int k0 = ks * 32 + ((lane >> 4) << 3);
    f16x8 v;
#pragma unroll
    for (int j = 0; j < 8; ++j) v[j] = (__fp16)src[co * 64 + k0 + j];
    wA[s] = v;
}

// ------- MFMA A-fragment prep, generalized K (proj_a Ci=128 ks4; ffn_a Ci=80 ks3) -----
__global__ __launch_bounds__(256) void prepA2_kernel(
    const float* __restrict__ pa, const float* __restrict__ fa,
    f16x8* __restrict__ wA2)
{
    int s = blockIdx.x * 256 + threadIdx.x;
    if (s >= 2560) return;
    const float* src; int base, Ci, ksteps;
    if (s < 1024)      { src = pa;        base = 0;    Ci = 128; ksteps = 4; }
    else if (s < 1792) { src = fa;        base = 1024; Ci = 80;  ksteps = 3; }
    else               { src = fa + 5120; base = 1792; Ci = 80;  ksteps = 3; }
    int r = s - base;
    int lane = r & 63;
    int u = r >> 6;
    int ks = u % ksteps;
    int cot = u / ksteps;
    int co = cot * 16 + (lane & 15);
    int k0 = ks * 32 + ((lane >> 4) << 3);
    f16x8 v;
#pragma unroll
    for (int j = 0; j < 8; ++j) {
        int k = k0 + j;
        v[j] = (k < Ci) ? (__fp16)src[co * Ci + k] : (__fp16)0.f;
    }
    wA2[s] = v;
}

// ------- MFMA A-fragment prep for conv3 (K = 576, k = tap*64 + ci) -------
__global__ __launch_bounds__(256) void prepA3_kernel(
    const float* __restrict__ co3, f16x8* __restrict__ wA3)
{
    int s = blockIdx.x * 256 + threadIdx.x;
    if (s >= 4608) return;
    int lane = s & 63;
    int u = s >> 6;
    int cot = u & 3;
    int t = u >> 2;
    int co = cot * 16 + (lane & 15);
    int k0 = t * 32 + ((lane >> 4) << 3);
    f16x8 v;
#pragma unroll
    for (int j = 0; j < 8; ++j) {
        int k = k0 + j;
        int tap = k >> 6, ci = k & 63;
        v[j] = (__fp16)co3[(co * 64 + ci) * 9 + tap];
    }
    wA3[s] = v;
}

// ---------------- LayerNorm over 64 channels, f16 output ----------------
__global__ __launch_bounds__(256, 2) void ln_kernel(
    const float* __restrict__ in, const float* __restrict__ w,
    const float* __restrict__ b, __fp16* __restrict__ out)
{
    int p = blockIdx.x * 256 + threadIdx.x;
    int bb = blockIdx.y;
    if (p >= HWP) return;
    const float* ib = in + (size_t)bb * 64 * HWP + p;
    float v[64];
    float mu = 0.f;
#pragma unroll
    for (int c = 0; c < 64; ++c) { v[c] = ib[(size_t)c * HWP]; mu += v[c]; }
    mu *= (1.f / 64.f);
    float var = 0.f;
#pragma unroll
    for (int c = 0; c < 64; ++c) { float d = v[c] - mu; var += d * d; }
    var *= (1.f / 64.f);
    float r = rsqrtf(var + 1e-6f);
    __fp16* ob = out + (size_t)bb * 64 * HWP + p;
#pragma unroll
    for (int c = 0; c < 64; ++c) ob[(size_t)c * HWP] = (__fp16)((v[c] - mu) * r * w[c] + b[c]);
}

// ------- FUSED LayerNorm + 1x1 conv via MFMA (Ci=64, f32 input, f16 output) -----------
__global__ __launch_bounds__(256, 2) void lnconvh_kernel(
    const float* __restrict__ in,   // (B,64,H,W) f32
    const float* __restrict__ lnw, const float* __restrict__ lnb,
    const f16x8* __restrict__ wA,   // Ci=64 layout
    const float* __restrict__ bias, __fp16* __restrict__ outh,
    int Co, int do_gelu)
{
    int lane = threadIdx.x & 63;
    int wv = threadIdx.x >> 6;
    int px0 = blockIdx.x * 256 + wv * 64;
    if (px0 >= HWP) return;
    int bb = blockIdx.z;
    int cot0 = blockIdx.y * 4;
    int nCot = (Co >> 4) - cot0; if (nCot > 4) nCot = 4;
    int row = lane >> 4;
    int colp = lane & 15;

    float wl[2][8], bl[2][8];
#pragma unroll
    for (int ks = 0; ks < 2; ++ks)
#pragma unroll
        for (int j = 0; j < 8; ++j) {
            int c = ks * 32 + row * 8 + j;
            wl[ks][j] = lnw[c];
            bl[ks][j] = lnb[c];
        }

    f16x8 afr[4][2];
#pragma unroll
    for (int c = 0; c < 4; ++c)
        if (c < nCot)
#pragma unroll
            for (int ks = 0; ks < 2; ++ks)
                afr[c][ks] = wA[(((cot0 + c) * 2 + ks) << 6) + lane];

    fx4 acc[4][4];
#pragma unroll
    for (int c = 0; c < 4; ++c)
#pragma unroll
        for (int nt = 0; nt < 4; ++nt)
#pragma unroll
            for (int r = 0; r < 4; ++r) acc[c][nt][r] = 0.f;

    const float* ib = in + (size_t)bb * 64 * HWP;
#pragma unroll
    for (int nt = 0; nt < 4; ++nt) {
        int px = px0 + nt * 16 + colp;
        float xv[2][8];
        float s = 0.f, sq = 0.f;
#pragma unroll
        for (int ks = 0; ks < 2; ++ks)
#pragma unroll
            for (int j = 0; j < 8; ++j) {
                float v = ib[(size_t)(ks * 32 + row * 8 + j) * HWP + px];
                xv[ks][j] = v;
                s += v; sq += v * v;
            }
        s += __shfl_xor(s, 16, 64);  sq += __shfl_xor(sq, 16, 64);
        s += __shfl_xor(s, 32, 64);  sq += __shfl_xor(sq, 32, 64);
        float mu = s * (1.f / 64.f);
        float var = sq * (1.f / 64.f) - mu * mu;
        float rr = rsqrtf(fmaxf(var, 0.f) + 1e-6f);
#pragma unroll
        for (int ks = 0; ks < 2; ++ks) {
            union { f16x8 v; f16x2 h[4]; } bu;
#pragma unroll
            for (int j2 = 0; j2 < 4; ++j2) {
                float v0 = (xv[ks][2 * j2]     - mu) * rr * wl[ks][2 * j2]     + bl[ks][2 * j2];
                float v1 = (xv[ks][2 * j2 + 1] - mu) * rr * wl[ks][2 * j2 + 1] + bl[ks][2 * j2 + 1];
                bu.h[j2] = pk2(v0, v1);
            }
#pragma unroll
            for (int c = 0; c < 4; ++c)
                if (c < nCot)
                    acc[c][nt] = __builtin_amdgcn_mfma_f32_16x16x32_f16(afr[c][ks], bu.v, acc[c][nt], 0, 0, 0);
        }
    }

#pragma unroll
    for (int c = 0; c < 4; ++c) {
        if (c < nCot) {
#pragma unroll
            for (int r = 0; r < 4; ++r) {
                int co = (cot0 + c) * 16 + row * 4 + r;
                float bv = bias[co];
#pragma unroll
                for (int nt = 0; nt < 4; ++nt) {
                    int px = px0 + nt * 16 + colp;
                    float v = acc[c][nt][r] + bv;
                    if (do_gelu) v = gelu_f(v);
                    outh[((size_t)bb * Co + co) * HWP + px] = (__fp16)v;
                }
            }
        }
    }
}

// ---------------- 1x1 conv via MFMA, f32 input, outh/outf flags ----------------
__global__ __launch_bounds__(256, 3) void conv1x1_mfma_kernel(
    const float* __restrict__ in, const f16x8* __restrict__ wA,
    const float* __restrict__ bias, float* outf, __fp16* outh,
    int Co, int do_gelu, int do_add)
{
    int lane = threadIdx.x & 63;
    int wv = threadIdx.x >> 6;
    int px0 = blockIdx.x * 256 + wv * 64;
    if (px0 >= HWP) return;
    int bb = blockIdx.z;
    int cot0 = blockIdx.y * 4;
    int nCot = (Co >> 4) - cot0; if (nCot > 4) nCot = 4;
    int row = lane >> 4;
    int colp = lane & 15;

    fx4 acc[4][4];
#pragma unroll
    for (int c = 0; c < 4; ++c)
#pragma unroll
        for (int nt = 0; nt < 4; ++nt)
#pragma unroll
            for (int r = 0; r < 4; ++r) acc[c][nt][r] = 0.f;

    const float* ib = in + (size_t)bb * 64 * HWP;
#pragma unroll
    for (int ks = 0; ks < 2; ++ks) {
        f16x8 afr[4];
#pragma unroll
        for (int c = 0; c < 4; ++c)
            if (c < nCot) afr[c] = wA[(((cot0 + c) * 2 + ks) << 6) + lane];
#pragma unroll
        for (int nt = 0; nt < 4; ++nt) {
            int px = px0 + nt * 16 + colp;
            const float* bp = ib + (size_t)(ks * 32 + row * 8) * HWP + px;
            union { f16x8 v; f16x2 h[4]; } bu;
            bu.h[0] = pk2(bp[0],              bp[(size_t)1 * HWP]);
            bu.h[1] = pk2(bp[(size_t)2 * HWP], bp[(size_t)3 * HWP]);
            bu.h[2] = pk2(bp[(size_t)4 * HWP], bp[(size_t)5 * HWP]);
            bu.h[3] = pk2(bp[(size_t)6 * HWP], bp[(size_t)7 * HWP]);
#pragma unroll
            for (int c = 0; c < 4; ++c)
                if (c < nCot)
                    acc[c][nt] = __builtin_amdgcn_mfma_f32_16x16x32_f16(afr[c], bu.v, acc[c][nt], 0, 0, 0);
        }
    }

#pragma unroll
    for (int c = 0; c < 4; ++c) {
        if (c < nCot) {
#pragma unroll
            for (int r = 0; r < 4; ++r) {
                int co = (cot0 + c) * 16 + row * 4 + r;
                float bv = bias[co];
#pragma unroll
                for (int nt = 0; nt < 4; ++nt) {
                    int px = px0 + nt * 16 + colp;
                    float v = acc[c][nt][r] + bv;
                    if (do_gelu) v = gelu_f(v);
                    if (outh) {
                        outh[((size_t)bb * Co + co) * HWP + px] = (__fp16)v;
                    } else {
                        float* op = outf + ((size_t)bb * Co + co) * HWP;
                        if (do_add) v += op[px];
                        op[px] = v;
                    }
                }
            }
        }
    }
}

// ---------------- 1x1 conv via MFMA, f16 input, generalized (Ci, ksteps, Co) -----------
__global__ __launch_bounds__(256, 3) void convh_kernel(
    const __fp16* __restrict__ in,   // (B,Ci,H,W) f16
    const f16x8* __restrict__ wA,
    const float* __restrict__ bias, float* outf, __fp16* outh,
    int Ci, int ksteps, int Co, int do_gelu, int do_add)
{
    int lane = threadIdx.x & 63;
    int wv = threadIdx.x >> 6;
    int px0 = blockIdx.x * 256 + wv * 64;
    if (px0 >= HWP) return;
    int bb = blockIdx.z;
    int cot0 = blockIdx.y * 4;
    int nCot = (Co >> 4) - cot0; if (nCot > 4) nCot = 4;
    int row = lane >> 4;
    int colp = lane & 15;

    fx4 acc[4][4];
#pragma unroll
    for (int c = 0; c < 4; ++c)
#pragma unroll
        for (int nt = 0; nt < 4; ++nt)
#pragma unroll
            for (int r = 0; r < 4; ++r) acc[c][nt][r] = 0.f;

    const __fp16* ib = in + (size_t)bb * Ci * HWP;
    for (int ks = 0; ks < ksteps; ++ks) {
        f16x8 afr[4];
#pragma unroll
        for (int c = 0; c < 4; ++c)
            if (c < nCot) afr[c] = wA[(((cot0 + c) * ksteps + ks) << 6) + lane];
        int k0 = ks * 32 + row * 8;
        bool ok = (k0 < Ci);
#pragma unroll
        for (int nt = 0; nt < 4; ++nt) {
            int px = px0 + nt * 16 + colp;
            f16x8 bv;
            if (ok) {
                const __fp16* bp = ib + (size_t)k0 * HWP + px;
#pragma unroll
                for (int j = 0; j < 8; ++j) bv[j] = bp[(size_t)j * HWP];
            } else {
#pragma unroll
                for (int j = 0; j < 8; ++j) bv[j] = (__fp16)0.f;
            }
#pragma unroll
            for (int c = 0; c < 4; ++c)
                if (c < nCot)
                    acc[c][nt] = __builtin_amdgcn_mfma_f32_16x16x32_f16(afr[c], bv, acc[c][nt], 0, 0, 0);
        }
    }

#pragma unroll
    for (int c = 0; c < 4; ++c) {
        if (c < nCot) {
#pragma unroll
            for (int r = 0; r < 4; ++r) {
                int co = (cot0 + c) * 16 + row * 4 + r;
                float bv = bias[co];
#pragma unroll
                for (int nt = 0; nt < 4; ++nt) {
                    int px = px0 + nt * 16 + colp;
                    float v = acc[c][nt][r] + bv;
                    if (do_gelu) v = gelu_f(v);
                    if (outh) {
                        outh[((size_t)bb * Co + co) * HWP + px] = (__fp16)v;
                    } else {
                        float* op = outf + ((size_t)bb * Co + co) * HWP;
                        if (do_add) v += op[px];
                        op[px] = v;
                    }
                }
            }
        }
    }
}

// ---------------- conv3 via MFMA: f16 input, 9 shifted taps, bias+skip fused ----------
__global__ __launch_bounds__(256, 2) void conv3_mfma_kernel(
    const __fp16* __restrict__ in,
    const f16x8* __restrict__ wA3,
    const float* __restrict__ bias, const float* __restrict__ skip,
    float* __restrict__ out)
{
    int lane = threadIdx.x & 63;
    int wv = threadIdx.x >> 6;
    int px0 = blockIdx.x * 256 + wv * 64;
    if (px0 >= HWP) return;
    int bb = blockIdx.z;
    int row = lane >> 4;
    int colp = lane & 15;

    fx4 acc[4][4];
#pragma unroll
    for (int c = 0; c < 4; ++c)
#pragma unroll
        for (int nt = 0; nt < 4; ++nt)
#pragma unroll
            for (int r = 0; r < 4; ++r) acc[c][nt][r] = 0.f;

    int py[4], pxx[4];
#pragma unroll
    for (int nt = 0; nt < 4; ++nt) {
        int p = px0 + nt * 16 + colp;
        py[nt] = p / WW;
        pxx[nt] = p - py[nt] * WW;
    }

    const __fp16* ib = in + (size_t)bb * 64 * HWP;
    for (int t = 0; t < 18; ++t) {
        int tap = t >> 1, ks = t & 1;
        int dy = tap / 3 - 1, dx = tap % 3 - 1;
        f16x8 afr[4];
#pragma unroll
        for (int c = 0; c < 4; ++c) afr[c] = wA3[((t * 4 + c) << 6) + lane];
        const __fp16* kb = ib + (size_t)(ks * 32 + row * 8) * HWP;
#pragma unroll
        for (int nt = 0; nt < 4; ++nt) {
            int yy = py[nt] + dy, xx = pxx[nt] + dx;
            f16x8 bv;
            if ((unsigned)yy < HH && (unsigned)xx < WW) {
                const __fp16* bp = kb + yy * WW + xx;
#pragma unroll
                for (int j = 0; j < 8; ++j) bv[j] = bp[(size_t)j * HWP];
            } else {
#pragma unroll
                for (int j = 0; j < 8; ++j) bv[j] = (__fp16)0.f;
            }
#pragma unroll
            for (int c = 0; c < 4; ++c)
                acc[c][nt] = __builtin_amdgcn_mfma_f32_16x16x32_f16(afr[c], bv, acc[c][nt], 0, 0, 0);
        }
    }

#pragma unroll
    for (int c = 0; c < 4; ++c) {
#pragma unroll
        for (int r = 0; r < 4; ++r) {
            int co = c * 16 + row * 4 + r;
            float bv = bias[co];
            const float* sb = skip + ((size_t)bb * 64 + co) * HWP;
            float* op = out + ((size_t)bb * 64 + co) * HWP;
#pragma unroll
            for (int nt = 0; nt < 4; ++nt) {
                int px = px0 + nt * 16 + colp;
                op[px] = acc[c][nt][r] + bv + sb[px];
            }
        }
    }
}

// ------- dwgelu: v = gelu(dwconv3x3(in)) + in, f16 in/out; channel-PAIR packed ----
__global__ __launch_bounds__(256, 4) void dwgelu_kernel(
    const __fp16* __restrict__ in,  // (B,Ci,H,W) f16
    const float* __restrict__ dw,   // (Ci,9)
    const float* __restrict__ db,   // (Ci)
    __fp16* __restrict__ vout,      // (B,Ci,H,W) f16
    int Ci)
{
    __shared__ f16x2 s_p[8][18 * DPS];   // 8 ci-pairs x 18x24 = 13.8 KB
    int tid = threadIdx.x;
    int tx = tid & 15, ty = tid >> 4;
    int x0 = blockIdx.x * 16, y0 = blockIdx.y * 16;
    int part = blockIdx.z & 3;
    int bb = blockIdx.z >> 2;
    int cic = Ci >> 2;
    int cbase = part * cic;
    int npair = cic >> 1;
    int x = x0 + tx, y = y0 + ty;
    bool inb = (x < WW && y < HH);
    int p = y * WW + x;

    const __fp16* ibase = in + (size_t)bb * Ci * HWP;
    __fp16* obase = vout + (size_t)bb * Ci * HWP;
    for (int p0 = 0; p0 < npair; p0 += 8) {
        int chunk = npair - p0; if (chunk > 8) chunk = 8;
        __syncthreads();
        for (int i = tid; i < chunk * 324; i += 256) {
            int pi = i / 324; int r = i - pi * 324;
            int py = r / 18, px = r - py * 18;
            int yy = y0 + py - 1, xx = x0 + px - 1;
            f16x2 v;
            v[0] = (__fp16)0.f; v[1] = (__fp16)0.f;
            if ((unsigned)yy < HH && (unsigned)xx < WW) {
                int c0 = cbase + 2 * (p0 + pi);
                int gp = yy * WW + xx;
                v[0] = ibase[(size_t)c0 * HWP + gp];
                v[1] = ibase[(size_t)(c0 + 1) * HWP + gp];
            }
            s_p[pi][py * DPS + px] = v;
        }
        __syncthreads();
        if (inb) {
            for (int pi = 0; pi < chunk; ++pi) {
                int c0 = cbase + 2 * (p0 + pi);
                f16x2 s;
                s[0] = (__fp16)db[c0];
                s[1] = (__fp16)db[c0 + 1];
#pragma unroll
                for (int ky = 0; ky < 3; ++ky)
#pragma unroll
                    for (int kx = 0; kx < 3; ++kx) {
                        f16x2 wv = pk2(dw[c0 * 9 + ky * 3 + kx], dw[(c0 + 1) * 9 + ky * 3 + kx]);
                        s += s_p[pi][(ty + ky) * DPS + tx + kx] * wv;
                    }
                f16x2 center = s_p[pi][(ty + 1) * DPS + tx + 1];
                float v0 = gelu_f((float)s[0]) + (float)center[0];
                float v1 = gelu_f((float)s[1]) + (float)center[1];
                obase[(size_t)c0 * HWP + p]       = (__fp16)v0;
                obase[(size_t)(c0 + 1) * HWP + p] = (__fp16)v1;
            }
        }
    }
}

// ---------------- attention v8: b128 LDS reads, exp2 domain, XCD swizzle ----------
// launch_bounds (128,4): hints >4 force VGPR below the s16 live range -> scratch
// spill (r23/r24). s_k2 kept [100][4] (16B rows) for single ds_read_b128 per key.
__global__ __launch_bounds__(128, 4) void winattn2_kernel(
    const __fp16* __restrict__ qkv, // (B,192,H,W) f16
    const float* __restrict__ rpb,  // (8,361)
    __fp16* __restrict__ out)       // (B,64,H,W) f16
{
    __shared__ __align__(16) f16x2 s_k2[100][4];    // [key][ch-pair], 16B rows
    __shared__ __align__(16) __fp16 s_vT[8][104];   // [cc][key], 208B rows (16B mult), keys 100..103 zero
    __shared__ float s_b[361];

    int lin = blockIdx.x + 400 * (blockIdx.y + 8 * blockIdx.z);
    int swz = (lin & 7) * 1600 + (lin >> 3);
    int win = swz % 400;
    int head = (swz / 400) & 7;
    int bb = swz / 3200;
    int wy = win / 20, wx = win - wy * 20;
    int tid = threadIdx.x;

    const float log2e = 1.4426950408889634f;
    for (int i = tid; i < 361; i += 128) s_b[i] = rpb[head * 361 + i] * log2e;
    if (tid < 32) s_vT[tid >> 2][100 + (tid & 3)] = (__fp16)0.f;

    int ty = tid / 10, tx = tid - ty * 10;
    f16x2 q2[4];
    if (tid < 100) {
        int y = wy * 10 + ty, x = wx * 10 + tx;
        int gp = y * WW + x;
        const __fp16* qb = qkv + ((size_t)bb * 192 + head * 8) * HWP + gp;
        const __fp16* kb = qb + (size_t)64 * HWP;
        const __fp16* vb = qb + (size_t)128 * HWP;
        const float qsc = 0.3535533905932738f * log2e;
#pragma unroll
        for (int c2 = 0; c2 < 4; ++c2) {
            q2[c2] = pk2((float)qb[(size_t)(2 * c2) * HWP] * qsc,
                         (float)qb[(size_t)(2 * c2 + 1) * HWP] * qsc);
            f16x2 kv;
            kv[0] = kb[(size_t)(2 * c2) * HWP];
            kv[1] = kb[(size_t)(2 * c2 + 1) * HWP];
            s_k2[tid][c2] = kv;
        }
#pragma unroll
        for (int cc = 0; cc < 8; ++cc)
            s_vT[cc][tid] = vb[(size_t)cc * HWP];
    }
    __syncthreads();

    if (tid < 100) {
        const float* brow = s_b + (180 - ty * 19 - tx);

        // pairs 50,51 are sentinels: exp2(-3e4 - m) == 0, so the 13-block PV
        // loop (13*8 = 104 keys) is exact with zero-padded s_vT.
        f16x2 s16[52];
        s16[50] = pk2(-30000.f, -30000.f);
        s16[51] = pk2(-30000.f, -30000.f);
        float m = -1e30f;
#pragma unroll
        for (int i = 0; i < 50; ++i) {
            const int k0 = 2 * i, k1 = 2 * i + 1;
            const int c0 = (k0 / 10) * 19 + (k0 % 10);
            const int c1 = (k1 / 10) * 19 + (k1 % 10);
            float s0 = brow[c0];
            float s1 = brow[c1];
            union { f16x8 v; f16x2 h[4]; } kv0, kv1;
            kv0.v = *(const f16x8*)&s_k2[k0][0];
            kv1.v = *(const f16x8*)&s_k2[k1][0];
#pragma unroll
            for (int c2 = 0; c2 < 4; ++c2) {
                s0 = fdot2f(q2[c2], kv0.h[c2], s0);
                s1 = fdot2f(q2[c2], kv1.h[c2], s1);
            }
            m = fmaxf(m, fmaxf(s0, s1));
            s16[i] = pk2(s0, s1);
        }
        float l = 0.f;
        float o[8];
#pragma unroll
        for (int cc = 0; cc < 8; ++cc) o[cc] = 0.f;
#pragma unroll
        for (int blk = 0; blk < 13; ++blk) {
            f16x2 e2[4];
#pragma unroll
            for (int t = 0; t < 4; ++t) {
                int i = blk * 4 + t;
                float e0 = exp2f((float)s16[i][0] - m);
                float e1 = exp2f((float)s16[i][1] - m);
                l += e0 + e1;
                e2[t] = pk2(e0, e1);
            }
#pragma unroll
            for (int cc = 0; cc < 8; ++cc) {
                union { f16x8 v; f16x2 h[4]; } vv;
                vv.v = *(const f16x8*)&s_vT[cc][blk * 8];
#pragma unroll
                for (int t = 0; t < 4; ++t)
                    o[cc] = fdot2f(e2[t], vv.h[t], o[cc]);
            }
        }
        float rl = 1.f / l;
        int y = wy * 10 + ty, x = wx * 10 + tx;
        __fp16* ob = out + ((size_t)bb * 64 + head * 8) * HWP + y * WW + x;
#pragma unroll
        for (int cc = 0; cc < 8; ++cc) ob[(size_t)cc * HWP] = (__fp16)(o[cc] * rl);
    }
}

// ------- geometric ensemble -> D4-orbit table, ci-PAIR packed: (pair, rep, co) f16x2 ----
__global__ __launch_bounds__(256) void geo_kernel(
    const float* __restrict__ k, f16x2* __restrict__ out)
{
    int i = blockIdx.x * 256 + threadIdx.x;
    if (i >= 3584) return;
    int p = i / 448;
    int r = i - p * 448;
    int rep = r >> 4, co = r & 15;
    int a = 0, rr = rep;
    while (rr >= 7 - a) { rr -= 7 - a; ++a; }
    int b2 = a + rr;
    int y = 6 + a, x = 6 + b2;
    float sv[2];
#pragma unroll
    for (int t = 0; t < 2; ++t) {
        int ci = 2 * p + t;
        const float* kb = k + (co * 16 + ci) * 169;
        float s = kb[y * 13 + x] + kb[y * 13 + (12 - x)] + kb[(12 - y) * 13 + x] + kb[(12 - y) * 13 + (12 - x)]
                + kb[(12 - x) * 13 + y] + kb[x * 13 + y] + kb[(12 - x) * 13 + (12 - y)] + kb[x * 13 + (12 - y)];
        sv[t] = s * 0.125f;
    }
    f16x2 v;
    v[0] = (__fp16)sv[0];
    v[1] = (__fp16)sv[1];
    out[i] = v;
}

// ---------------- global mean over H,W of first-16 channels (float4) ----------------
__global__ __launch_bounds__(256) void gmean_kernel(
    const float* __restrict__ in, float* __restrict__ g)
{
    int bc = blockIdx.x;
    int bb = bc >> 4, c = bc & 15;
    const float4* p = (const float4*)(in + ((size_t)bb * 64 + c) * HWP);
    float s = 0.f;
    for (int i = threadIdx.x; i < NP4; i += 256) {
        float4 v = p[i];
        s += (v.x + v.y) + (v.z + v.w);
    }
#pragma unroll
    for (int off = 32; off > 0; off >>= 1) s += __shfl_down(s, off);
    __shared__ float red[4];
    int wave = threadIdx.x >> 6;
    if ((threadIdx.x & 63) == 0) red[wave] = s;
    __syncthreads();
    if (threadIdx.x == 0)
        g[bc] = (red[0] + red[1] + red[2] + red[3]) * (1.f / 40000.f);
}

// ---------------- tiny MLP -> dynamic 3x3 kernels ----------------
__global__ __launch_bounds__(192) void dynk_kernel(
    const float* __restrict__ g, const float* __restrict__ w1, const float* __restrict__ b1,
    const float* __restrict__ w2, const float* __restrict__ b2, float* __restrict__ dk)
{
    int bb = blockIdx.x;
    __shared__ float s_g2[8];
    int tid = threadIdx.x;
    if (tid < 8) {
        float a = b1[tid];
        for (int c = 0; c < 16; ++c) a += w1[tid * 16 + c] * g[bb * 16 + c];
        s_g2[tid] = gelu_f(a);
    }
    __syncthreads();
    if (tid < 144) {
        float a = b2[tid];
#pragma unroll
        for (int i = 0; i < 8; ++i) a += w2[tid * 8 + i] * s_g2[i];
        dk[bb * 144 + tid] = a;
    }
}

// ------- 13x13 D4-symmetric conv via packed-pair orbit sums + dynamic depthwise 3x3 ----
__global__ __launch_bounds__(256, 6) void lkconv_kernel(
    const float* __restrict__ in,
    const f16x2* __restrict__ lkP,
    const float* __restrict__ dk,
    float* __restrict__ out)
{
    __shared__ f16x2 s_p[2][28 * LKS];
    int z = blockIdx.z;
    int bb = z >> 2, q = z & 3;
    int tid = threadIdx.x;
    int tx = tid & 15, ty = tid >> 4;
    int x0 = blockIdx.x * 16, y0 = blockIdx.y * 16;
    int x = x0 + tx, y = y0 + ty;

    const float* ib = in + ((size_t)bb * 64 + q * 4) * HWP;
    for (int i = tid; i < 2 * 784; i += 256) {
        int pi = i / 784; int r = i - pi * 784;
        int py = r / 28, px = r - py * 28;
        int yy = y0 + py - 6, xx = x0 + px - 6;
        f16x2 v = pk2(0.f, 0.f);
        if ((unsigned)yy < HH && (unsigned)xx < WW) {
            int gp = yy * WW + xx;
            v = pk2(ib[(size_t)(2 * pi) * HWP + gp], ib[(size_t)(2 * pi + 1) * HWP + gp]);
        }
        s_p[pi][py * LKS + px] = v;
    }
    __syncthreads();

    float acc[16];
#pragma unroll
    for (int co = 0; co < 16; ++co) acc[co] = 0.f;

#pragma unroll
    for (int pi = 0; pi < 2; ++pi) {
        f16x2 orb[28];
#pragma unroll
        for (int o = 0; o < 28; ++o) orb[o] = pk2(0.f, 0.f);
#pragma unroll
        for (int ky = 0; ky < 13; ++ky) {
#pragma unroll
            for (int kx = 0; kx < 13; ++kx) {
                const int a = (ky < 6) ? (6 - ky) : (ky - 6);
                const int b = (kx < 6) ? (6 - kx) : (kx - 6);
                const int lo = (a < b) ? a : b;
                const int hi = (a < b) ? b : a;
                const int idx = lo * 7 - (lo * (lo - 1)) / 2 + (hi - lo);
                orb[idx] += s_p[pi][(ty + ky) * LKS + tx + kx];
            }
        }
        const f16x2* wci = lkP + (size_t)(q * 2 + pi) * 28 * 16;
#pragma unroll
        for (int o = 0; o < 28; ++o) {
            f16x2 ov = orb[o];
            const f16x2* wr = wci + o * 16;
#pragma unroll
            for (int co = 0; co < 16; ++co) acc[co] = fdot2f(ov, wr[co], acc[co]);
        }
#pragma unroll
        for (int h = 0; h < 2; ++h) {
            int ci = q * 4 + 2 * pi + h;
            float d = 0.f;
            const float* dkr = dk + bb * 144 + ci * 9;
#pragma unroll
            for (int dy = 0; dy < 3; ++dy)
#pragma unroll
                for (int dx = 0; dx < 3; ++dx)
                    d += (float)s_p[pi][(ty + 5 + dy) * LKS + tx + 5 + dx][h] * dkr[dy * 3 + dx];
#pragma unroll
            for (int co = 0; co < 16; ++co) acc[co] += (co == ci) ? d : 0.f;
        }
    }

    if (x < WW && y < HH) {
        int p = y * WW + x;
        float* ob = out + (size_t)q * PARTSZ + (size_t)bb * 16 * HWP + p;
#pragma unroll
        for (int co = 0; co < 16; ++co) ob[(size_t)co * HWP] = acc[co];
    }
}

// ------- 1x1 conv over concat(sum of 4 x1 partials, y[16..63]), dot2; += xout -----
__global__ __launch_bounds__(256, 2) void pconv_add_kernel(
    const float* __restrict__ x1q,
    const float* __restrict__ yy,
    const f16x2* __restrict__ wt,
    const float* __restrict__ bias,
    float* __restrict__ xout)
{
    int p4 = blockIdx.x * 256 + threadIdx.x;
    int o0 = blockIdx.y * 16;
    int bb = blockIdx.z;
    if (p4 >= NP4) return;
    float4 acc[16];
#pragma unroll
    for (int j = 0; j < 16; ++j) {
        float bv = bias[o0 + j];
        acc[j] = make_float4(bv, bv, bv, bv);
    }
    const float4* xb0 = (const float4*)(x1q + (size_t)bb * 16 * HWP) + p4;
    const float4* xb1 = (const float4*)(x1q + PARTSZ + (size_t)bb * 16 * HWP) + p4;
    const float4* xb2 = (const float4*)(x1q + 2 * PARTSZ + (size_t)bb * 16 * HWP) + p4;
    const float4* xb3 = (const float4*)(x1q + 3 * PARTSZ + (size_t)bb * 16 * HWP) + p4;
    for (int c2 = 0; c2 < 8; ++c2) {
        int ca = 2 * c2, cb = 2 * c2 + 1;
        float4 a0 = xb0[(size_t)ca * NP4], a1 = xb1[(size_t)ca * NP4];
        float4 a2 = xb2[(size_t)ca * NP4], a3 = xb3[(size_t)ca * NP4];
        float4 s0;
        s0.x = (a0.x + a1.x) + (a2.x + a3.x);
        s0.y = (a0.y + a1.y) + (a2.y + a3.y);
        s0.z = (a0.z + a1.z) + (a2.z + a3.z);
        s0.w = (a0.w + a1.w) + (a2.w + a3.w);
        a0 = xb0[(size_t)cb * NP4]; a1 = xb1[(size_t)cb * NP4];
        a2 = xb2[(size_t)cb * NP4]; a3 = xb3[(size_t)cb * NP4];
        float4 s1;
        s1.x = (a0.x + a1.x) + (a2.x + a3.x);
        s1.y = (a0.y + a1.y) + (a2.y + a3.y);
        s1.z = (a0.z + a1.z) + (a2.z + a3.z);
        s1.w = (a0.w + a1.w) + (a2.w + a3.w);
        f16x2 px = pk2(s0.x, s1.x), py = pk2(s0.y, s1.y);
        f16x2 pz = pk2(s0.z, s1.z), pw = pk2(s0.w, s1.w);
        const f16x2* wr = wt + c2 * 64 + o0;
#pragma unroll
        for (int j = 0; j < 16; ++j) {
            f16x2 w = wr[j];
            acc[j].x = fdot2f(px, w, acc[j].x);
            acc[j].y = fdot2f(py, w, acc[j].y);
            acc[j].z = fdot2f(pz, w, acc[j].z);
            acc[j].w = fdot2f(pw, w, acc[j].w);
        }
    }
    const float4* yb = (const float4*)(yy + ((size_t)bb * 64 + 16) * HWP) + p4;
    for (int c2 = 8; c2 < 32; ++c2) {
        int cy = 2 * (c2 - 8);
        float4 s0 = yb[(size_t)cy * NP4];
        float4 s1 = yb[(size_t)(cy + 1) * NP4];
        f16x2 px = pk2(s0.x, s1.x), py = pk2(s0.y, s1.y);
        f16x2 pz = pk2(s0.z, s1.z), pw = pk2(s0.w, s1.w);
        const f16x2* wr = wt + c2 * 64 + o0;
#pragma unroll
        for (int j = 0; j < 16; ++j) {
            f16x2 w = wr[j];
            acc[j].x = fdot2f(px, w, acc[j].x);
            acc[j].y = fdot2f(py, w, acc[j].y);
            acc[j].z = fdot2f(pz, w, acc[j].z);
            acc[j].w = fdot2f(pw, w, acc[j].w);
        }
    }
    float4* ob = (float4*)(xout + ((size_t)bb * 64 + o0) * HWP) + p4;
#pragma unroll
    for (int j = 0; j < 16; ++j) {
        float4 old = ob[(size_t)j * NP4];
        old.x += acc[j].x; old.y += acc[j].y; old.z += acc[j].z; old.w += acc[j].w;
        ob[(size_t)j * NP4] = old;
    }
}

extern "C" void kernel_launch(void* const* d_in, const int* in_sizes, int n_in,
                              void* d_out, int out_size, void* d_ws, size_t ws_size,
                              hipStream_t stream)
{
    const float* x_in      = (const float*)d_in[0];
    const float* ln_proj_w = (const float*)d_in[1];
    const float* ln_proj_b = (const float*)d_in[2];
    const float* proj_p_w  = (const float*)d_in[3];
    const float* proj_p_b  = (const float*)d_in[4];
    const float* proj_d_w  = (const float*)d_in[5];
    const float* proj_d_b  = (const float*)d_in[6];
    const float* proj_a_w  = (const float*)d_in[7];
    const float* proj_a_b  = (const float*)d_in[8];
    const float* ln_attn_w = (const float*)d_in[9];
    const float* ln_attn_b = (const float*)d_in[10];
    const float* qkv_w     = (const float*)d_in[11];
    const float* qkv_b     = (const float*)d_in[12];
    const float* attn_o_w  = (const float*)d_in[13];
    const float* attn_o_b  = (const float*)d_in[14];
    const float* rpb       = (const float*)d_in[15];
    const float* dwcp1_w   = (const float*)d_in[16];
    const float* dwcp1_b   = (const float*)d_in[17];
    const float* dwcp2_w   = (const float*)d_in[18];
    const float* dwcp2_b   = (const float*)d_in[19];
    const float* pconv_w   = (const float*)d_in[20];
    const float* pconv_b   = (const float*)d_in[21];
    const float* ffn_p_w   = (const float*)d_in[22];
    const float* ffn_p_b   = (const float*)d_in[23];
    const float* ffn_d_w   = (const float*)d_in[24];
    const float* ffn_d_b   = (const float*)d_in[25];
    const float* ffn_a_w   = (const float*)d_in[26];
    const float* ffn_a_b   = (const float*)d_in[27];
    const float* ln_out_w  = (const float*)d_in[28];
    const float* ln_out_b  = (const float*)d_in[29];
    const float* conv_o_w  = (const float*)d_in[30];
    const float* conv_o_b  = (const float*)d_in[31];
    const float* plk       = (const float*)d_in[32];

    float* X  = (float*)d_out;
    float* ws = (float*)d_ws;

    float*  Y    = ws;
    __fp16* A16  = (__fp16*)ws;
    __fp16* R1h  = (__fp16*)(ws + 10240000);
    __fp16* QKVh = (__fp16*)(ws + 10240000);
    __fp16* Vh   = (__fp16*)(ws + 23040000);
    float*  R2Q  = ws + 33280000;
    f16x2* LKTH = (f16x2*)(ws + 43520000);
    float* GM   = ws + 43524096;
    float* DK   = GM + 64;
    f16x2* WTH  = (f16x2*)(DK + 576);
    f16x8* WAH  = (f16x8*)(DK + 576 + 4096);
    f16x8* WA2  = WAH + 4352;
    f16x8* WA3  = WA2 + 2560;

    dim3 b256(256);
    dim3 gLN(157, 4);
    dim3 gT16(13, 13, 16);

    prep_kernel<<<dim3(16), b256, 0, stream>>>(pconv_w, WTH);
    prepA_kernel<<<dim3(17), b256, 0, stream>>>(qkv_w, proj_p_w, attn_o_w, ffn_p_w, WAH);
    prepA2_kernel<<<dim3(10), b256, 0, stream>>>(proj_a_w, ffn_a_w, WA2);
    prepA3_kernel<<<dim3(18), b256, 0, stream>>>(conv_o_w, WA3);
    geo_kernel<<<dim3(14), b256, 0, stream>>>(plk, LKTH);

    // x = conv_ffn(LN(x)) [proj] — LN fused into the proj_p MFMA conv
    lnconvh_kernel<<<dim3(157, 2, 4), b256, 0, stream>>>(x_in, ln_proj_w, ln_proj_b,
                                                         WAH + 1536, proj_p_b, R1h, 128, 1);
    dwgelu_kernel<<<gT16, b256, 0, stream>>>(R1h, proj_d_w, proj_d_b, Vh, 128);
    convh_kernel<<<dim3(157, 1, 4), b256, 0, stream>>>(Vh, WA2 + 0, proj_a_b,
                                                       X, nullptr, 128, 4, 64, 0, 0);

    // x = x + window_attention(LN(x)) — LN fused into the qkv MFMA conv
    lnconvh_kernel<<<dim3(157, 3, 4), b256, 0, stream>>>(X, ln_attn_w, ln_attn_b,
                                                         WAH + 0, qkv_b, QKVh, 192, 0);
    winattn2_kernel<<<dim3(400, 8, 4), dim3(128), 0, stream>>>(QKVh, rpb, A16);
    convh_kernel<<<dim3(157, 1, 4), b256, 0, stream>>>(A16, WAH + 2560, attn_o_b,
                                                       X, nullptr, 64, 2, 64, 0, 1);

    for (int i = 0; i < 2; ++i) {
        conv1x1_mfma_kernel<<<dim3(157, 2, 4), b256, 0, stream>>>(X, WAH + 3072 + i * 640,
                                                                  ffn_p_b + i * 80, nullptr, R1h, 80, 1, 0);
        dwgelu_kernel<<<gT16, b256, 0, stream>>>(R1h, ffn_d_w + i * 720, ffn_d_b + i * 80, Vh, 80);
        convh_kernel<<<dim3(157, 1, 4), b256, 0, stream>>>(Vh, WA2 + 1024 + i * 768,
                                                           ffn_a_b + i * 64, Y, nullptr, 80, 3, 64, 0, 0);
        gmean_kernel<<<dim3(64), b256, 0, stream>>>(Y, GM);
        dynk_kernel<<<dim3(4), dim3(192), 0, stream>>>(GM, dwcp1_w + i * 128, dwcp1_b + i * 8,
                                                       dwcp2_w + i * 1152, dwcp2_b + i * 144, DK);
        lkconv_kernel<<<gT16, b256, 0, stream>>>(Y, LKTH, DK, R2Q);
        pconv_add_kernel<<<dim3(40, 4, 4), b256, 0, stream>>>(R2Q, Y, WTH + i * 2048, pconv_b + i * 64, X);
    }

    // x = conv3x3(LN(x)) + skip — LN standalone (halo stats), conv3 MFMA
    ln_kernel<<<gLN, b256, 0, stream>>>(X, ln_out_w, ln_out_b, A16);
    conv3_mfma_kernel<<<dim3(157, 1, 4), b256, 0, stream>>>(A16, WA3, conv_o_b, x_in, X);
}

// Round 27
// 822.398 us; speedup vs baseline: 1.0170x; 1.0170x over previous
//
#include <hip/hip_runtime.h>
#include <math.h>

#define HH 200
#define WW 200
#define HWP 40000
#define NP4 10000
#define BB 4

#define LKS 40   // lkconv LDS row stride (u32 entries)
#define DPS 24   // dwgelu LDS row stride
#define PARTSZ 2560000    // one (B,16,H,W) partial buffer (lkconv)

typedef __fp16 f16x2 __attribute__((ext_vector_type(2)));
typedef __fp16 f16x8 __attribute__((ext_vector_type(8)));
typedef float fx4 __attribute__((ext_vector_type(4)));

#if __has_builtin(__builtin_amdgcn_fdot2)
__device__ __forceinline__ float fdot2f(f16x2 a, f16x2 b, float c) {
    return __builtin_amdgcn_fdot2(a, b, c, false);
}
#else
__device__ __forceinline__ float fdot2f(f16x2 a, f16x2 b, float c) {
    return c + (float)a[0] * (float)b[0] + (float)a[1] * (float)b[1];
}
#endif

// native 2^x (v_exp_f32). Args here are always <= 0; large-negative flushes to 0,
// matching the sentinel semantics. ~1 instr vs ocml's ~6 (subnormal handling).
#if __has_builtin(__builtin_amdgcn_exp2f)
__device__ __forceinline__ float fexp2(float x) { return __builtin_amdgcn_exp2f(x); }
#else
__device__ __forceinline__ float fexp2(float x) { return exp2f(x); }
#endif

#if __has_builtin(__builtin_amdgcn_rcpf)
__device__ __forceinline__ float frcp(float x) { return __builtin_amdgcn_rcpf(x); }
#else
__device__ __forceinline__ float frcp(float x) { return 1.f / x; }
#endif

__device__ __forceinline__ f16x2 pk2(float a, float b) {
    return __builtin_amdgcn_cvt_pkrtz(a, b);
}

__device__ __forceinline__ float gelu_f(float x) {
    return 0.5f * x * (1.0f + erff(x * 0.7071067811865475f));
}

// ---------------- pconv weight pack (ci,co) f16x2 ----------------
__global__ __launch_bounds__(256) void prep_kernel(
    const float* __restrict__ pc, f16x2* __restrict__ wth)
{
    int i = blockIdx.x * 256 + threadIdx.x;
    if (i >= 4096) return;
    int w = i >> 11;
    int r = i & 2047;
    int c2 = r / 64, o = r - c2 * 64;
    const float* src = pc + w * 4096;
    f16x2 v;
    v[0] = (__fp16)src[o * 64 + 2 * c2];
    v[1] = (__fp16)src[o * 64 + 2 * c2 + 1];
    wth[w * 2048 + r] = v;
}

// ------- MFMA A-fragment prep for Ci=64 1x1 convs (ksteps=2) -------
__global__ __launch_bounds__(256) void prepA_kernel(
    const float* __restrict__ qkvw, const float* __restrict__ pp,
    const float* __restrict__ ao, const float* __restrict__ fp,
    f16x8* __restrict__ wA)
{
    int s = blockIdx.x * 256 + threadIdx.x;
    if (s >= 4352) return;
    const float* src;
    int base;
    if (s < 1536)      { src = qkvw;      base = 0; }
    else if (s < 2560) { src = pp;        base = 1536; }
    else if (s < 3072) { src = ao;        base = 2560; }
    else if (s < 3712) { src = fp;        base = 3072; }
    else               { src = fp + 5120; base = 3712; }
    int r = s - base;
    int lane = r & 63;
    int t = r >> 6;
    int ks = t & 1;
    int cot = t >> 1;
    int co = cot * 16 + (lane & 15);
    int k0 = ks * 32 + ((lane >> 4) << 3);
    f16x8 v;
#pragma unroll
    for (int j = 0; j < 8; ++j) v[j] = (__fp16)src[co * 64 + k0 + j];
    wA[s] = v;
}

// ------- MFMA A-fragment prep, generalized K (proj_a Ci=128 ks4; ffn_a Ci=80 ks3) -----
__global__ __launch_bounds__(256) void prepA2_kernel(
    const float* __restrict__ pa, const float* __restrict__ fa,
    f16x8* __restrict__ wA2)
{
    int s = blockIdx.x * 256 + threadIdx.x;
    if (s >= 2560) return;
    const float* src; int base, Ci, ksteps;
    if (s < 1024)      { src = pa;        base = 0;    Ci = 128; ksteps = 4; }
    else if (s < 1792) { src = fa;        base = 1024; Ci = 80;  ksteps = 3; }
    else               { src = fa + 5120; base = 1792; Ci = 80;  ksteps = 3; }
    int r = s - base;
    int lane = r & 63;
    int u = r >> 6;
    int ks = u % ksteps;
    int cot = u / ksteps;
    int co = cot * 16 + (lane & 15);
    int k0 = ks * 32 + ((lane >> 4) << 3);
    f16x8 v;
#pragma unroll
    for (int j = 0; j < 8; ++j) {
        int k = k0 + j;
        v[j] = (k < Ci) ? (__fp16)src[co * Ci + k] : (__fp16)0.f;
    }
    wA2[s] = v;
}

// ------- MFMA A-fragment prep for conv3 (K = 576, k = tap*64 + ci) -------
__global__ __launch_bounds__(256) void prepA3_kernel(
    const float* __restrict__ co3, f16x8* __restrict__ wA3)
{
    int s = blockIdx.x * 256 + threadIdx.x;
    if (s >= 4608) return;
    int lane = s & 63;
    int u = s >> 6;
    int cot = u & 3;
    int t = u >> 2;
    int co = cot * 16 + (lane & 15);
    int k0 = t * 32 + ((lane >> 4) << 3);
    f16x8 v;
#pragma unroll
    for (int j = 0; j < 8; ++j) {
        int k = k0 + j;
        int tap = k >> 6, ci = k & 63;
        v[j] = (__fp16)co3[(co * 64 + ci) * 9 + tap];
    }
    wA3[s] = v;
}

// ---------------- LayerNorm over 64 channels, f16 output ----------------
__global__ __launch_bounds__(256, 2) void ln_kernel(
    const float* __restrict__ in, const float* __restrict__ w,
    const float* __restrict__ b, __fp16* __restrict__ out)
{
    int p = blockIdx.x * 256 + threadIdx.x;
    int bb = blockIdx.y;
    if (p >= HWP) return;
    const float* ib = in + (size_t)bb * 64 * HWP + p;
    float v[64];
    float mu = 0.f;
#pragma unroll
    for (int c = 0; c < 64; ++c) { v[c] = ib[(size_t)c * HWP]; mu += v[c]; }
    mu *= (1.f / 64.f);
    float var = 0.f;
#pragma unroll
    for (int c = 0; c < 64; ++c) { float d = v[c] - mu; var += d * d; }
    var *= (1.f / 64.f);
    float r = rsqrtf(var + 1e-6f);
    __fp16* ob = out + (size_t)bb * 64 * HWP + p;
#pragma unroll
    for (int c = 0; c < 64; ++c) ob[(size_t)c * HWP] = (__fp16)((v[c] - mu) * r * w[c] + b[c]);
}

// ------- FUSED LayerNorm + 1x1 conv via MFMA (Ci=64, f32 input, f16 output) -----------
__global__ __launch_bounds__(256, 2) void lnconvh_kernel(
    const float* __restrict__ in,   // (B,64,H,W) f32
    const float* __restrict__ lnw, const float* __restrict__ lnb,
    const f16x8* __restrict__ wA,   // Ci=64 layout
    const float* __restrict__ bias, __fp16* __restrict__ outh,
    int Co, int do_gelu)
{
    int lane = threadIdx.x & 63;
    int wv = threadIdx.x >> 6;
    int px0 = blockIdx.x * 256 + wv * 64;
    if (px0 >= HWP) return;
    int bb = blockIdx.z;
    int cot0 = blockIdx.y * 4;
    int nCot = (Co >> 4) - cot0; if (nCot > 4) nCot = 4;
    int row = lane >> 4;
    int colp = lane & 15;

    float wl[2][8], bl[2][8];
#pragma unroll
    for (int ks = 0; ks < 2; ++ks)
#pragma unroll
        for (int j = 0; j < 8; ++j) {
            int c = ks * 32 + row * 8 + j;
            wl[ks][j] = lnw[c];
            bl[ks][j] = lnb[c];
        }

    f16x8 afr[4][2];
#pragma unroll
    for (int c = 0; c < 4; ++c)
        if (c < nCot)
#pragma unroll
            for (int ks = 0; ks < 2; ++ks)
                afr[c][ks] = wA[(((cot0 + c) * 2 + ks) << 6) + lane];

    fx4 acc[4][4];
#pragma unroll
    for (int c = 0; c < 4; ++c)
#pragma unroll
        for (int nt = 0; nt < 4; ++nt)
#pragma unroll
            for (int r = 0; r < 4; ++r) acc[c][nt][r] = 0.f;

    const float* ib = in + (size_t)bb * 64 * HWP;
#pragma unroll
    for (int nt = 0; nt < 4; ++nt) {
        int px = px0 + nt * 16 + colp;
        float xv[2][8];
        float s = 0.f, sq = 0.f;
#pragma unroll
        for (int ks = 0; ks < 2; ++ks)
#pragma unroll
            for (int j = 0; j < 8; ++j) {
                float v = ib[(size_t)(ks * 32 + row * 8 + j) * HWP + px];
                xv[ks][j] = v;
                s += v; sq += v * v;
            }
        s += __shfl_xor(s, 16, 64);  sq += __shfl_xor(sq, 16, 64);
        s += __shfl_xor(s, 32, 64);  sq += __shfl_xor(sq, 32, 64);
        float mu = s * (1.f / 64.f);
        float var = sq * (1.f / 64.f) - mu * mu;
        float rr = rsqrtf(fmaxf(var, 0.f) + 1e-6f);
#pragma unroll
        for (int ks = 0; ks < 2; ++ks) {
            union { f16x8 v; f16x2 h[4]; } bu;
#pragma unroll
            for (int j2 = 0; j2 < 4; ++j2) {
                float v0 = (xv[ks][2 * j2]     - mu) * rr * wl[ks][2 * j2]     + bl[ks][2 * j2];
                float v1 = (xv[ks][2 * j2 + 1] - mu) * rr * wl[ks][2 * j2 + 1] + bl[ks][2 * j2 + 1];
                bu.h[j2] = pk2(v0, v1);
            }
#pragma unroll
            for (int c = 0; c < 4; ++c)
                if (c < nCot)
                    acc[c][nt] = __builtin_amdgcn_mfma_f32_16x16x32_f16(afr[c][ks], bu.v, acc[c][nt], 0, 0, 0);
        }
    }

#pragma unroll
    for (int c = 0; c < 4; ++c) {
        if (c < nCot) {
#pragma unroll
            for (int r = 0; r < 4; ++r) {
                int co = (cot0 + c) * 16 + row * 4 + r;
                float bv = bias[co];
#pragma unroll
                for (int nt = 0; nt < 4; ++nt) {
                    int px = px0 + nt * 16 + colp;
                    float v = acc[c][nt][r] + bv;
                    if (do_gelu) v = gelu_f(v);
                    outh[((size_t)bb * Co + co) * HWP + px] = (__fp16)v;
                }
            }
        }
    }
}

// ---------------- 1x1 conv via MFMA, f32 input, outh/outf flags ----------------
__global__ __launch_bounds__(256, 3) void conv1x1_mfma_kernel(
    const float* __restrict__ in, const f16x8* __restrict__ wA,
    const float* __restrict__ bias, float* outf, __fp16* outh,
    int Co, int do_gelu, int do_add)
{
    int lane = threadIdx.x & 63;
    int wv = threadIdx.x >> 6;
    int px0 = blockIdx.x * 256 + wv * 64;
    if (px0 >= HWP) return;
    int bb = blockIdx.z;
    int cot0 = blockIdx.y * 4;
    int nCot = (Co >> 4) - cot0; if (nCot > 4) nCot = 4;
    int row = lane >> 4;
    int colp = lane & 15;

    fx4 acc[4][4];
#pragma unroll
    for (int c = 0; c < 4; ++c)
#pragma unroll
        for (int nt = 0; nt < 4; ++nt)
#pragma unroll
            for (int r = 0; r < 4; ++r) acc[c][nt][r] = 0.f;

    const float* ib = in + (size_t)bb * 64 * HWP;
#pragma unroll
    for (int ks = 0; ks < 2; ++ks) {
        f16x8 afr[4];
#pragma unroll
        for (int c = 0; c < 4; ++c)
            if (c < nCot) afr[c] = wA[(((cot0 + c) * 2 + ks) << 6) + lane];
#pragma unroll
        for (int nt = 0; nt < 4; ++nt) {
            int px = px0 + nt * 16 + colp;
            const float* bp = ib + (size_t)(ks * 32 + row * 8) * HWP + px;
            union { f16x8 v; f16x2 h[4]; } bu;
            bu.h[0] = pk2(bp[0],              bp[(size_t)1 * HWP]);
            bu.h[1] = pk2(bp[(size_t)2 * HWP], bp[(size_t)3 * HWP]);
            bu.h[2] = pk2(bp[(size_t)4 * HWP], bp[(size_t)5 * HWP]);
            bu.h[3] = pk2(bp[(size_t)6 * HWP], bp[(size_t)7 * HWP]);
#pragma unroll
            for (int c = 0; c < 4; ++c)
                if (c < nCot)
                    acc[c][nt] = __builtin_amdgcn_mfma_f32_16x16x32_f16(afr[c], bu.v, acc[c][nt], 0, 0, 0);
        }
    }

#pragma unroll
    for (int c = 0; c < 4; ++c) {
        if (c < nCot) {
#pragma unroll
            for (int r = 0; r < 4; ++r) {
                int co = (cot0 + c) * 16 + row * 4 + r;
                float bv = bias[co];
#pragma unroll
                for (int nt = 0; nt < 4; ++nt) {
                    int px = px0 + nt * 16 + colp;
                    float v = acc[c][nt][r] + bv;
                    if (do_gelu) v = gelu_f(v);
                    if (outh) {
                        outh[((size_t)bb * Co + co) * HWP + px] = (__fp16)v;
                    } else {
                        float* op = outf + ((size_t)bb * Co + co) * HWP;
                        if (do_add) v += op[px];
                        op[px] = v;
                    }
                }
            }
        }
    }
}

// ---------------- 1x1 conv via MFMA, f16 input, generalized (Ci, ksteps, Co) -----------
__global__ __launch_bounds__(256, 3) void convh_kernel(
    const __fp16* __restrict__ in,   // (B,Ci,H,W) f16
    const f16x8* __restrict__ wA,
    const float* __restrict__ bias, float* outf, __fp16* outh,
    int Ci, int ksteps, int Co, int do_gelu, int do_add)
{
    int lane = threadIdx.x & 63;
    int wv = threadIdx.x >> 6;
    int px0 = blockIdx.x * 256 + wv * 64;
    if (px0 >= HWP) return;
    int bb = blockIdx.z;
    int cot0 = blockIdx.y * 4;
    int nCot = (Co >> 4) - cot0; if (nCot > 4) nCot = 4;
    int row = lane >> 4;
    int colp = lane & 15;

    fx4 acc[4][4];
#pragma unroll
    for (int c = 0; c < 4; ++c)
#pragma unroll
        for (int nt = 0; nt < 4; ++nt)
#pragma unroll
            for (int r = 0; r < 4; ++r) acc[c][nt][r] = 0.f;

    const __fp16* ib = in + (size_t)bb * Ci * HWP;
    for (int ks = 0; ks < ksteps; ++ks) {
        f16x8 afr[4];
#pragma unroll
        for (int c = 0; c < 4; ++c)
            if (c < nCot) afr[c] = wA[(((cot0 + c) * ksteps + ks) << 6) + lane];
        int k0 = ks * 32 + row * 8;
        bool ok = (k0 < Ci);
#pragma unroll
        for (int nt = 0; nt < 4; ++nt) {
            int px = px0 + nt * 16 + colp;
            f16x8 bv;
            if (ok) {
                const __fp16* bp = ib + (size_t)k0 * HWP + px;
#pragma unroll
                for (int j = 0; j < 8; ++j) bv[j] = bp[(size_t)j * HWP];
            } else {
#pragma unroll
                for (int j = 0; j < 8; ++j) bv[j] = (__fp16)0.f;
            }
#pragma unroll
            for (int c = 0; c < 4; ++c)
                if (c < nCot)
                    acc[c][nt] = __builtin_amdgcn_mfma_f32_16x16x32_f16(afr[c], bv, acc[c][nt], 0, 0, 0);
        }
    }

#pragma unroll
    for (int c = 0; c < 4; ++c) {
        if (c < nCot) {
#pragma unroll
            for (int r = 0; r < 4; ++r) {
                int co = (cot0 + c) * 16 + row * 4 + r;
                float bv = bias[co];
#pragma unroll
                for (int nt = 0; nt < 4; ++nt) {
                    int px = px0 + nt * 16 + colp;
                    float v = acc[c][nt][r] + bv;
                    if (do_gelu) v = gelu_f(v);
                    if (outh) {
                        outh[((size_t)bb * Co + co) * HWP + px] = (__fp16)v;
                    } else {
                        float* op = outf + ((size_t)bb * Co + co) * HWP;
                        if (do_add) v += op[px];
                        op[px] = v;
                    }
                }
            }
        }
    }
}

// ---------------- conv3 via MFMA: f16 input, 9 shifted taps, bias+skip fused ----------
__global__ __launch_bounds__(256, 3) void conv3_mfma_kernel(
    const __fp16* __restrict__ in,
    const f16x8* __restrict__ wA3,
    const float* __restrict__ bias, const float* __restrict__ skip,
    float* __restrict__ out)
{
    int lane = threadIdx.x & 63;
    int wv = threadIdx.x >> 6;
    int px0 = blockIdx.x * 256 + wv * 64;
    if (px0 >= HWP) return;
    int bb = blockIdx.z;
    int row = lane >> 4;
    int colp = lane & 15;

    fx4 acc[4][4];
#pragma unroll
    for (int c = 0; c < 4; ++c)
#pragma unroll
        for (int nt = 0; nt < 4; ++nt)
#pragma unroll
            for (int r = 0; r < 4; ++r) acc[c][nt][r] = 0.f;

    int py[4], pxx[4];
#pragma unroll
    for (int nt = 0; nt < 4; ++nt) {
        int p = px0 + nt * 16 + colp;
        py[nt] = p / WW;
        pxx[nt] = p - py[nt] * WW;
    }

    const __fp16* ib = in + (size_t)bb * 64 * HWP;
    for (int t = 0; t < 18; ++t) {
        int tap = t >> 1, ks = t & 1;
        int dy = tap / 3 - 1, dx = tap % 3 - 1;
        f16x8 afr[4];
#pragma unroll
        for (int c = 0; c < 4; ++c) afr[c] = wA3[((t * 4 + c) << 6) + lane];
        const __fp16* kb = ib + (size_t)(ks * 32 + row * 8) * HWP;
#pragma unroll
        for (int nt = 0; nt < 4; ++nt) {
            int yy = py[nt] + dy, xx = pxx[nt] + dx;
            f16x8 bv;
            if ((unsigned)yy < HH && (unsigned)xx < WW) {
                const __fp16* bp = kb + yy * WW + xx;
#pragma unroll
                for (int j = 0; j < 8; ++j) bv[j] = bp[(size_t)j * HWP];
            } else {
#pragma unroll
                for (int j = 0; j < 8; ++j) bv[j] = (__fp16)0.f;
            }
#pragma unroll
            for (int c = 0; c < 4; ++c)
                acc[c][nt] = __builtin_amdgcn_mfma_f32_16x16x32_f16(afr[c], bv, acc[c][nt], 0, 0, 0);
        }
    }

#pragma unroll
    for (int c = 0; c < 4; ++c) {
#pragma unroll
        for (int r = 0; r < 4; ++r) {
            int co = c * 16 + row * 4 + r;
            float bv = bias[co];
            const float* sb = skip + ((size_t)bb * 64 + co) * HWP;
            float* op = out + ((size_t)bb * 64 + co) * HWP;
#pragma unroll
            for (int nt = 0; nt < 4; ++nt) {
                int px = px0 + nt * 16 + colp;
                op[px] = acc[c][nt][r] + bv + sb[px];
            }
        }
    }
}

// ------- dwgelu: v = gelu(dwconv3x3(in)) + in, f16 in/out; channel-PAIR packed ----
__global__ __launch_bounds__(256, 4) void dwgelu_kernel(
    const __fp16* __restrict__ in,  // (B,Ci,H,W) f16
    const float* __restrict__ dw,   // (Ci,9)
    const float* __restrict__ db,   // (Ci)
    __fp16* __restrict__ vout,      // (B,Ci,H,W) f16
    int Ci)
{
    __shared__ f16x2 s_p[8][18 * DPS];   // 8 ci-pairs x 18x24 = 13.8 KB
    int tid = threadIdx.x;
    int tx = tid & 15, ty = tid >> 4;
    int x0 = blockIdx.x * 16, y0 = blockIdx.y * 16;
    int part = blockIdx.z & 3;
    int bb = blockIdx.z >> 2;
    int cic = Ci >> 2;
    int cbase = part * cic;
    int npair = cic >> 1;
    int x = x0 + tx, y = y0 + ty;
    bool inb = (x < WW && y < HH);
    int p = y * WW + x;

    const __fp16* ibase = in + (size_t)bb * Ci * HWP;
    __fp16* obase = vout + (size_t)bb * Ci * HWP;
    for (int p0 = 0; p0 < npair; p0 += 8) {
        int chunk = npair - p0; if (chunk > 8) chunk = 8;
        __syncthreads();
        for (int i = tid; i < chunk * 324; i += 256) {
            int pi = i / 324; int r = i - pi * 324;
            int py = r / 18, px = r - py * 18;
            int yy = y0 + py - 1, xx = x0 + px - 1;
            f16x2 v;
            v[0] = (__fp16)0.f; v[1] = (__fp16)0.f;
            if ((unsigned)yy < HH && (unsigned)xx < WW) {
                int c0 = cbase + 2 * (p0 + pi);
                int gp = yy * WW + xx;
                v[0] = ibase[(size_t)c0 * HWP + gp];
                v[1] = ibase[(size_t)(c0 + 1) * HWP + gp];
            }
            s_p[pi][py * DPS + px] = v;
        }
        __syncthreads();
        if (inb) {
            for (int pi = 0; pi < chunk; ++pi) {
                int c0 = cbase + 2 * (p0 + pi);
                f16x2 s;
                s[0] = (__fp16)db[c0];
                s[1] = (__fp16)db[c0 + 1];
#pragma unroll
                for (int ky = 0; ky < 3; ++ky)
#pragma unroll
                    for (int kx = 0; kx < 3; ++kx) {
                        f16x2 wv = pk2(dw[c0 * 9 + ky * 3 + kx], dw[(c0 + 1) * 9 + ky * 3 + kx]);
                        s += s_p[pi][(ty + ky) * DPS + tx + kx] * wv;
                    }
                f16x2 center = s_p[pi][(ty + 1) * DPS + tx + 1];
                float v0 = gelu_f((float)s[0]) + (float)center[0];
                float v1 = gelu_f((float)s[1]) + (float)center[1];
                obase[(size_t)c0 * HWP + p]       = (__fp16)v0;
                obase[(size_t)(c0 + 1) * HWP + p] = (__fp16)v1;
            }
        }
    }
}

// ---------------- attention v9: b128 LDS reads, native exp2, XCD swizzle ----------
// launch_bounds (128,4): hints >4 force VGPR below the s16 live range -> scratch
// spill (r23/r24). s_k2 kept [100][4] (16B rows) for single ds_read_b128 per key.
__global__ __launch_bounds__(128, 4) void winattn2_kernel(
    const __fp16* __restrict__ qkv, // (B,192,H,W) f16
    const float* __restrict__ rpb,  // (8,361)
    __fp16* __restrict__ out)       // (B,64,H,W) f16
{
    __shared__ __align__(16) f16x2 s_k2[100][4];    // [key][ch-pair], 16B rows
    __shared__ __align__(16) __fp16 s_vT[8][104];   // [cc][key], 208B rows (16B mult), keys 100..103 zero
    __shared__ float s_b[361];

    int lin = blockIdx.x + 400 * (blockIdx.y + 8 * blockIdx.z);
    int swz = (lin & 7) * 1600 + (lin >> 3);
    int win = swz % 400;
    int head = (swz / 400) & 7;
    int bb = swz / 3200;
    int wy = win / 20, wx = win - wy * 20;
    int tid = threadIdx.x;

    const float log2e = 1.4426950408889634f;
    for (int i = tid; i < 361; i += 128) s_b[i] = rpb[head * 361 + i] * log2e;
    if (tid < 32) s_vT[tid >> 2][100 + (tid & 3)] = (__fp16)0.f;

    int ty = tid / 10, tx = tid - ty * 10;
    f16x2 q2[4];
    if (tid < 100) {
        int y = wy * 10 + ty, x = wx * 10 + tx;
        int gp = y * WW + x;
        const __fp16* qb = qkv + ((size_t)bb * 192 + head * 8) * HWP + gp;
        const __fp16* kb = qb + (size_t)64 * HWP;
        const __fp16* vb = qb + (size_t)128 * HWP;
        const float qsc = 0.3535533905932738f * log2e;
#pragma unroll
        for (int c2 = 0; c2 < 4; ++c2) {
            q2[c2] = pk2((float)qb[(size_t)(2 * c2) * HWP] * qsc,
                         (float)qb[(size_t)(2 * c2 + 1) * HWP] * qsc);
            f16x2 kv;
            kv[0] = kb[(size_t)(2 * c2) * HWP];
            kv[1] = kb[(size_t)(2 * c2 + 1) * HWP];
            s_k2[tid][c2] = kv;
        }
#pragma unroll
        for (int cc = 0; cc < 8; ++cc)
            s_vT[cc][tid] = vb[(size_t)cc * HWP];
    }
    __syncthreads();

    if (tid < 100) {
        const float* brow = s_b + (180 - ty * 19 - tx);

        // pairs 50,51 are sentinels: exp2(-3e4 - m) flushes to 0, so the 13-block
        // PV loop (13*8 = 104 keys) is exact with zero-padded s_vT.
        f16x2 s16[52];
        s16[50] = pk2(-30000.f, -30000.f);
        s16[51] = pk2(-30000.f, -30000.f);
        float m = -1e30f;
#pragma unroll
        for (int i = 0; i < 50; ++i) {
            const int k0 = 2 * i, k1 = 2 * i + 1;
            const int c0 = (k0 / 10) * 19 + (k0 % 10);
            const int c1 = (k1 / 10) * 19 + (k1 % 10);
            float s0 = brow[c0];
            float s1 = brow[c1];
            union { f16x8 v; f16x2 h[4]; } kv0, kv1;
            kv0.v = *(const f16x8*)&s_k2[k0][0];
            kv1.v = *(const f16x8*)&s_k2[k1][0];
#pragma unroll
            for (int c2 = 0; c2 < 4; ++c2) {
                s0 = fdot2f(q2[c2], kv0.h[c2], s0);
                s1 = fdot2f(q2[c2], kv1.h[c2], s1);
            }
            m = fmaxf(m, fmaxf(s0, s1));
            s16[i] = pk2(s0, s1);
        }
        float l = 0.f;
        float o[8];
#pragma unroll
        for (int cc = 0; cc < 8; ++cc) o[cc] = 0.f;
#pragma unroll
        for (int blk = 0; blk < 13; ++blk) {
            f16x2 e2[4];
#pragma unroll
            for (int t = 0; t < 4; ++t) {
                int i = blk * 4 + t;
                float e0 = fexp2((float)s16[i][0] - m);
                float e1 = fexp2((float)s16[i][1] - m);
                l += e0 + e1;
                e2[t] = pk2(e0, e1);
            }
#pragma unroll
            for (int cc = 0; cc < 8; ++cc) {
                union { f16x8 v; f16x2 h[4]; } vv;
                vv.v = *(const f16x8*)&s_vT[cc][blk * 8];
#pragma unroll
                for (int t = 0; t < 4; ++t)
                    o[cc] = fdot2f(e2[t], vv.h[t], o[cc]);
            }
        }
        float rl = frcp(l);
        int y = wy * 10 + ty, x = wx * 10 + tx;
        __fp16* ob = out + ((size_t)bb * 64 + head * 8) * HWP + y * WW + x;
#pragma unroll
        for (int cc = 0; cc < 8; ++cc) ob[(size_t)cc * HWP] = (__fp16)(o[cc] * rl);
    }
}

// ------- geometric ensemble -> D4-orbit table, ci-PAIR packed: (pair, rep, co) f16x2 ----
__global__ __launch_bounds__(256) void geo_kernel(
    const float* __restrict__ k, f16x2* __restrict__ out)
{
    int i = blockIdx.x * 256 + threadIdx.x;
    if (i >= 3584) return;
    int p = i / 448;
    int r = i - p * 448;
    int rep = r >> 4, co = r & 15;
    int a = 0, rr = rep;
    while (rr >= 7 - a) { rr -= 7 - a; ++a; }
    int b2 = a + rr;
    int y = 6 + a, x = 6 + b2;
    float sv[2];
#pragma unroll
    for (int t = 0; t < 2; ++t) {
        int ci = 2 * p + t;
        const float* kb = k + (co * 16 + ci) * 169;
        float s = kb[y * 13 + x] + kb[y * 13 + (12 - x)] + kb[(12 - y) * 13 + x] + kb[(12 - y) * 13 + (12 - x)]
                + kb[(12 - x) * 13 + y] + kb[x * 13 + y] + kb[(12 - x) * 13 + (12 - y)] + kb[x * 13 + (12 - y)];
        sv[t] = s * 0.125f;
    }
    f16x2 v;
    v[0] = (__fp16)sv[0];
    v[1] = (__fp16)sv[1];
    out[i] = v;
}

// ---------------- global mean over H,W of first-16 channels (float4) ----------------
__global__ __launch_bounds__(256) void gmean_kernel(
    const float* __restrict__ in, float* __restrict__ g)
{
    int bc = blockIdx.x;
    int bb = bc >> 4, c = bc & 15;
    const float4* p = (const float4*)(in + ((size_t)bb * 64 + c) * HWP);
    float s = 0.f;
    for (int i = threadIdx.x; i < NP4; i += 256) {
        float4 v = p[i];
        s += (v.x + v.y) + (v.z + v.w);
    }
#pragma unroll
    for (int off = 32; off > 0; off >>= 1) s += __shfl_down(s, off);
    __shared__ float red[4];
    int wave = threadIdx.x >> 6;
    if ((threadIdx.x & 63) == 0) red[wave] = s;
    __syncthreads();
    if (threadIdx.x == 0)
        g[bc] = (red[0] + red[1] + red[2] + red[3]) * (1.f / 40000.f);
}

// ---------------- tiny MLP -> dynamic 3x3 kernels ----------------
__global__ __launch_bounds__(192) void dynk_kernel(
    const float* __restrict__ g, const float* __restrict__ w1, const float* __restrict__ b1,
    const float* __restrict__ w2, const float* __restrict__ b2, float* __restrict__ dk)
{
    int bb = blockIdx.x;
    __shared__ float s_g2[8];
    int tid = threadIdx.x;
    if (tid < 8) {
        float a = b1[tid];
        for (int c = 0; c < 16; ++c) a += w1[tid * 16 + c] * g[bb * 16 + c];
        s_g2[tid] = gelu_f(a);
    }
    __syncthreads();
    if (tid < 144) {
        float a = b2[tid];
#pragma unroll
        for (int i = 0; i < 8; ++i) a += w2[tid * 8 + i] * s_g2[i];
        dk[bb * 144 + tid] = a;
    }
}

// ------- 13x13 D4-symmetric conv via packed-pair orbit sums + dynamic depthwise 3x3 ----
__global__ __launch_bounds__(256, 6) void lkconv_kernel(
    const float* __restrict__ in,
    const f16x2* __restrict__ lkP,
    const float* __restrict__ dk,
    float* __restrict__ out)
{
    __shared__ f16x2 s_p[2][28 * LKS];
    int z = blockIdx.z;
    int bb = z >> 2, q = z & 3;
    int tid = threadIdx.x;
    int tx = tid & 15, ty = tid >> 4;
    int x0 = blockIdx.x * 16, y0 = blockIdx.y * 16;
    int x = x0 + tx, y = y0 + ty;

    const float* ib = in + ((size_t)bb * 64 + q * 4) * HWP;
    for (int i = tid; i < 2 * 784; i += 256) {
        int pi = i / 784; int r = i - pi * 784;
        int py = r / 28, px = r - py * 28;
        int yy = y0 + py - 6, xx = x0 + px - 6;
        f16x2 v = pk2(0.f, 0.f);
        if ((unsigned)yy < HH && (unsigned)xx < WW) {
            int gp = yy * WW + xx;
            v = pk2(ib[(size_t)(2 * pi) * HWP + gp], ib[(size_t)(2 * pi + 1) * HWP + gp]);
        }
        s_p[pi][py * LKS + px] = v;
    }
    __syncthreads();

    float acc[16];
#pragma unroll
    for (int co = 0; co < 16; ++co) acc[co] = 0.f;

#pragma unroll
    for (int pi = 0; pi < 2; ++pi) {
        f16x2 orb[28];
#pragma unroll
        for (int o = 0; o < 28; ++o) orb[o] = pk2(0.f, 0.f);
#pragma unroll
        for (int ky = 0; ky < 13; ++ky) {
#pragma unroll
            for (int kx = 0; kx < 13; ++kx) {
                const int a = (ky < 6) ? (6 - ky) : (ky - 6);
                const int b = (kx < 6) ? (6 - kx) : (kx - 6);
                const int lo = (a < b) ? a : b;
                const int hi = (a < b) ? b : a;
                const int idx = lo * 7 - (lo * (lo - 1)) / 2 + (hi - lo);
                orb[idx] += s_p[pi][(ty + ky) * LKS + tx + kx];
            }
        }
        const f16x2* wci = lkP + (size_t)(q * 2 + pi) * 28 * 16;
#pragma unroll
        for (int o = 0; o < 28; ++o) {
            f16x2 ov = orb[o];
            const f16x2* wr = wci + o * 16;
#pragma unroll
            for (int co = 0; co < 16; ++co) acc[co] = fdot2f(ov, wr[co], acc[co]);
        }
#pragma unroll
        for (int h = 0; h < 2; ++h) {
            int ci = q * 4 + 2 * pi + h;
            float d = 0.f;
            const float* dkr = dk + bb * 144 + ci * 9;
#pragma unroll
            for (int dy = 0; dy < 3; ++dy)
#pragma unroll
                for (int dx = 0; dx < 3; ++dx)
                    d += (float)s_p[pi][(ty + 5 + dy) * LKS + tx + 5 + dx][h] * dkr[dy * 3 + dx];
#pragma unroll
            for (int co = 0; co < 16; ++co) acc[co] += (co == ci) ? d : 0.f;
        }
    }

    if (x < WW && y < HH) {
        int p = y * WW + x;
        float* ob = out + (size_t)q * PARTSZ + (size_t)bb * 16 * HWP + p;
#pragma unroll
        for (int co = 0; co < 16; ++co) ob[(size_t)co * HWP] = acc[co];
    }
}

// ------- 1x1 conv over concat(sum of 4 x1 partials, y[16..63]), dot2; += xout -----
__global__ __launch_bounds__(256, 2) void pconv_add_kernel(
    const float* __restrict__ x1q,
    const float* __restrict__ yy,
    const f16x2* __restrict__ wt,
    const float* __restrict__ bias,
    float* __restrict__ xout)
{
    int p4 = blockIdx.x * 256 + threadIdx.x;
    int o0 = blockIdx.y * 16;
    int bb = blockIdx.z;
    if (p4 >= NP4) return;
    float4 acc[16];
#pragma unroll
    for (int j = 0; j < 16; ++j) {
        float bv = bias[o0 + j];
        acc[j] = make_float4(bv, bv, bv, bv);
    }
    const float4* xb0 = (const float4*)(x1q + (size_t)bb * 16 * HWP) + p4;
    const float4* xb1 = (const float4*)(x1q + PARTSZ + (size_t)bb * 16 * HWP) + p4;
    const float4* xb2 = (const float4*)(x1q + 2 * PARTSZ + (size_t)bb * 16 * HWP) + p4;
    const float4* xb3 = (const float4*)(x1q + 3 * PARTSZ + (size_t)bb * 16 * HWP) + p4;
    for (int c2 = 0; c2 < 8; ++c2) {
        int ca = 2 * c2, cb = 2 * c2 + 1;
        float4 a0 = xb0[(size_t)ca * NP4], a1 = xb1[(size_t)ca * NP4];
        float4 a2 = xb2[(size_t)ca * NP4], a3 = xb3[(size_t)ca * NP4];
        float4 s0;
        s0.x = (a0.x + a1.x) + (a2.x + a3.x);
        s0.y = (a0.y + a1.y) + (a2.y + a3.y);
        s0.z = (a0.z + a1.z) + (a2.z + a3.z);
        s0.w = (a0.w + a1.w) + (a2.w + a3.w);
        a0 = xb0[(size_t)cb * NP4]; a1 = xb1[(size_t)cb * NP4];
        a2 = xb2[(size_t)cb * NP4]; a3 = xb3[(size_t)cb * NP4];
        float4 s1;
        s1.x = (a0.x + a1.x) + (a2.x + a3.x);
        s1.y = (a0.y + a1.y) + (a2.y + a3.y);
        s1.z = (a0.z + a1.z) + (a2.z + a3.z);
        s1.w = (a0.w + a1.w) + (a2.w + a3.w);
        f16x2 px = pk2(s0.x, s1.x), py = pk2(s0.y, s1.y);
        f16x2 pz = pk2(s0.z, s1.z), pw = pk2(s0.w, s1.w);
        const f16x2* wr = wt + c2 * 64 + o0;
#pragma unroll
        for (int j = 0; j < 16; ++j) {
            f16x2 w = wr[j];
            acc[j].x = fdot2f(px, w, acc[j].x);
            acc[j].y = fdot2f(py, w, acc[j].y);
            acc[j].z = fdot2f(pz, w, acc[j].z);
            acc[j].w = fdot2f(pw, w, acc[j].w);
        }
    }
    const float4* yb = (const float4*)(yy + ((size_t)bb * 64 + 16) * HWP) + p4;
    for (int c2 = 8; c2 < 32; ++c2) {
        int cy = 2 * (c2 - 8);
        float4 s0 = yb[(size_t)cy * NP4];
        float4 s1 = yb[(size_t)(cy + 1) * NP4];
        f16x2 px = pk2(s0.x, s1.x), py = pk2(s0.y, s1.y);
        f16x2 pz = pk2(s0.z, s1.z), pw = pk2(s0.w, s1.w);
        const f16x2* wr = wt + c2 * 64 + o0;
#pragma unroll
        for (int j = 0; j < 16; ++j) {
            f16x2 w = wr[j];
            acc[j].x = fdot2f(px, w, acc[j].x);
            acc[j].y = fdot2f(py, w, acc[j].y);
            acc[j].z = fdot2f(pz, w, acc[j].z);
            acc[j].w = fdot2f(pw, w, acc[j].w);
        }
    }
    float4* ob = (float4*)(xout + ((size_t)bb * 64 + o0) * HWP) + p4;
#pragma unroll
    for (int j = 0; j < 16; ++j) {
        float4 old = ob[(size_t)j * NP4];
        old.x += acc[j].x; old.y += acc[j].y; old.z += acc[j].z; old.w += acc[j].w;
        ob[(size_t)j * NP4] = old;
    }
}

extern "C" void kernel_launch(void* const* d_in, const int* in_sizes, int n_in,
                              void* d_out, int out_size, void* d_ws, size_t ws_size,
                              hipStream_t stream)
{
    const float* x_in      = (const float*)d_in[0];
    const float* ln_proj_w = (const float*)d_in[1];
    const float* ln_proj_b = (const float*)d_in[2];
    const float* proj_p_w  = (const float*)d_in[3];
    const float* proj_p_b  = (const float*)d_in[4];
    const float* proj_d_w  = (const float*)d_in[5];
    const float* proj_d_b  = (const float*)d_in[6];
    const float* proj_a_w  = (const float*)d_in[7];
    const float* proj_a_b  = (const float*)d_in[8];
    const float* ln_attn_w = (const float*)d_in[9];
    const float* ln_attn_b = (const float*)d_in[10];
    const float* qkv_w     = (const float*)d_in[11];
    const float* qkv_b     = (const float*)d_in[12];
    const float* attn_o_w  = (const float*)d_in[13];
    const float* attn_o_b  = (const float*)d_in[14];
    const float* rpb       = (const float*)d_in[15];
    const float* dwcp1_w   = (const float*)d_in[16];
    const float* dwcp1_b   = (const float*)d_in[17];
    const float* dwcp2_w   = (const float*)d_in[18];
    const float* dwcp2_b   = (const float*)d_in[19];
    const float* pconv_w   = (const float*)d_in[20];
    const float* pconv_b   = (const float*)d_in[21];
    const float* ffn_p_w   = (const float*)d_in[22];
    const float* ffn_p_b   = (const float*)d_in[23];
    const float* ffn_d_w   = (const float*)d_in[24];
    const float* ffn_d_b   = (const float*)d_in[25];
    const float* ffn_a_w   = (const float*)d_in[26];
    const float* ffn_a_b   = (const float*)d_in[27];
    const float* ln_out_w  = (const float*)d_in[28];
    const float* ln_out_b  = (const float*)d_in[29];
    const float* conv_o_w  = (const float*)d_in[30];
    const float* conv_o_b  = (const float*)d_in[31];
    const float* plk       = (const float*)d_in[32];

    float* X  = (float*)d_out;
    float* ws = (float*)d_ws;

    float*  Y    = ws;
    __fp16* A16  = (__fp16*)ws;
    __fp16* R1h  = (__fp16*)(ws + 10240000);
    __fp16* QKVh = (__fp16*)(ws + 10240000);
    __fp16* Vh   = (__fp16*)(ws + 23040000);
    float*  R2Q  = ws + 33280000;
    f16x2* LKTH = (f16x2*)(ws + 43520000);
    float* GM   = ws + 43524096;
    float* DK   = GM + 64;
    f16x2* WTH  = (f16x2*)(DK + 576);
    f16x8* WAH  = (f16x8*)(DK + 576 + 4096);
    f16x8* WA2  = WAH + 4352;
    f16x8* WA3  = WA2 + 2560;

    dim3 b256(256);
    dim3 gLN(157, 4);
    dim3 gT16(13, 13, 16);

    prep_kernel<<<dim3(16), b256, 0, stream>>>(pconv_w, WTH);
    prepA_kernel<<<dim3(17), b256, 0, stream>>>(qkv_w, proj_p_w, attn_o_w, ffn_p_w, WAH);
    prepA2_kernel<<<dim3(10), b256, 0, stream>>>(proj_a_w, ffn_a_w, WA2);
    prepA3_kernel<<<dim3(18), b256, 0, stream>>>(conv_o_w, WA3);
    geo_kernel<<<dim3(14), b256, 0, stream>>>(plk, LKTH);

    // x = conv_ffn(LN(x)) [proj] — LN fused into the proj_p MFMA conv
    lnconvh_kernel<<<dim3(157, 2, 4), b256, 0, stream>>>(x_in, ln_proj_w, ln_proj_b,
                                                         WAH + 1536, proj_p_b, R1h, 128, 1);
    dwgelu_kernel<<<gT16, b256, 0, stream>>>(R1h, proj_d_w, proj_d_b, Vh, 128);
    convh_kernel<<<dim3(157, 1, 4), b256, 0, stream>>>(Vh, WA2 + 0, proj_a_b,
                                                       X, nullptr, 128, 4, 64, 0, 0);

    // x = x + window_attention(LN(x)) — LN fused into the qkv MFMA conv
    lnconvh_kernel<<<dim3(157, 3, 4), b256, 0, stream>>>(X, ln_attn_w, ln_attn_b,
                                                         WAH + 0, qkv_b, QKVh, 192, 0);
    winattn2_kernel<<<dim3(400, 8, 4), dim3(128), 0, stream>>>(QKVh, rpb, A16);
    convh_kernel<<<dim3(157, 1, 4), b256, 0, stream>>>(A16, WAH + 2560, attn_o_b,
                                                       X, nullptr, 64, 2, 64, 0, 1);

    for (int i = 0; i < 2; ++i) {
        conv1x1_mfma_kernel<<<dim3(157, 2, 4), b256, 0, stream>>>(X, WAH + 3072 + i * 640,
                                                                  ffn_p_b + i * 80, nullptr, R1h, 80, 1, 0);
        dwgelu_kernel<<<gT16, b256, 0, stream>>>(R1h, ffn_d_w + i * 720, ffn_d_b + i * 80, Vh, 80);
        convh_kernel<<<dim3(157, 1, 4), b256, 0, stream>>>(Vh, WA2 + 1024 + i * 768,
                                                           ffn_a_b + i * 64, Y, nullptr, 80, 3, 64, 0, 0);
        gmean_kernel<<<dim3(64), b256, 0, stream>>>(Y, GM);
        dynk_kernel<<<dim3(4), dim3(192), 0, stream>>>(GM, dwcp1_w + i * 128, dwcp1_b + i * 8,
                                                       dwcp2_w + i * 1152, dwcp2_b + i * 144, DK);
        lkconv_kernel<<<gT16, b256, 0, stream>>>(Y, LKTH, DK, R2Q);
        pconv_add_kernel<<<dim3(40, 4, 4), b256, 0, stream>>>(R2Q, Y, WTH + i * 2048, pconv_b + i * 64, X);
    }

    // x = conv3x3(LN(x)) + skip — LN standalone (halo stats), conv3 MFMA
    ln_kernel<<<gLN, b256, 0, stream>>>(X, ln_out_w, ln_out_b, A16);
    conv3_mfma_kernel<<<dim3(157, 1, 4), b256, 0, stream>>>(A16, WA3, conv_o_b, x_in, X);
}